// Round 1
// baseline (2080.880 us; speedup 1.0000x reference)
//
#include <hip/hip_runtime.h>
#include <cstdint>
#include <cstddef>

#define NT    64
#define CDIM  128
#define NHEAD 4
#define DHEAD 32
#define NB1   2048
#define RATIO 4
#define SCALE 0.17677669529663687f

union F4 { float4 v; float a[4]; };

__device__ __forceinline__ float bf2f(uint32_t u) {
    union { uint32_t i; float f; } c; c.i = u << 16; return c.f;
}
__device__ __forceinline__ uint32_t f2bf(float f) {
    union { float f; uint32_t i; } c; c.f = f;
    return (c.i + 0x7FFFu + ((c.i >> 16) & 1u)) >> 16;  // RNE
}

// bias_ws[h][n][m] = rpb_table[rel_index[n*64+m]*NHEAD + h]
__global__ __launch_bounds__(256) void bias_prep_k(
    const float* __restrict__ rpb, const int* __restrict__ rel,
    float* __restrict__ bias_ws)
{
    int idx  = blockIdx.x * 256 + threadIdx.x;   // 16384 total
    int h    = idx >> 12;
    int pair = idx & 4095;
    bias_ws[idx] = rpb[rel[pair] * NHEAD + h];
}

// q_ws[b][n][c] = (x1[b] @ qkv1_w^T + qkv1_b) * SCALE
__global__ __launch_bounds__(256) void q_proj_k(
    const float* __restrict__ x1, const float* __restrict__ w1,
    const float* __restrict__ b1v, float* __restrict__ q_ws)
{
    __shared__ __align__(16) float xs[NT * CDIM];   // 8192 f
    __shared__ __align__(16) float wch[32 * 132];   // transposed weight chunk

    const int tid = threadIdx.x;
    const int b   = blockIdx.x;
    const int tn  = tid >> 5;        // 0..7  -> rows 8*tn..
    const int tc  = tid & 31;        // 0..31 -> cols 4*tc..
    const int n0  = tn * 8, c0 = tc * 4;

    const float* xb = x1 + (size_t)b * (NT * CDIM);
#pragma unroll
    for (int i = 0; i < 8; ++i) {
        int idx = tid + i * 256;
        reinterpret_cast<float4*>(xs)[idx] = reinterpret_cast<const float4*>(xb)[idx];
    }

    float acc[8][4];
#pragma unroll
    for (int i = 0; i < 8; ++i)
#pragma unroll
        for (int j = 0; j < 4; ++j) acc[i][j] = 0.f;

    for (int kc = 0; kc < 4; ++kc) {
        __syncthreads();
#pragma unroll
        for (int i = 0; i < 4; ++i) {
            int idx = tid + i * 256;      // 0..1023
            int c = idx >> 3, k4 = idx & 7;
            F4 w4; w4.v = reinterpret_cast<const float4*>(w1 + c * CDIM + kc * 32)[k4];
#pragma unroll
            for (int e = 0; e < 4; ++e) wch[(k4 * 4 + e) * 132 + c] = w4.a[e];
        }
        __syncthreads();
        for (int k4 = 0; k4 < 8; ++k4) {
            const int k = kc * 32 + k4 * 4;
            F4 xv[8];
#pragma unroll
            for (int i = 0; i < 8; ++i)
                xv[i].v = *reinterpret_cast<const float4*>(&xs[(n0 + i) * CDIM + k]);
#pragma unroll
            for (int kk = 0; kk < 4; ++kk) {
                F4 wv; wv.v = *reinterpret_cast<const float4*>(&wch[(k4 * 4 + kk) * 132 + c0]);
#pragma unroll
                for (int i = 0; i < 8; ++i) {
                    float xk = xv[i].a[kk];
#pragma unroll
                    for (int e = 0; e < 4; ++e)
                        acc[i][e] = fmaf(xk, wv.a[e], acc[i][e]);
                }
            }
        }
    }

    F4 bv; bv.v = *reinterpret_cast<const float4*>(b1v + c0);
    float* qb = q_ws + (size_t)b * (NT * CDIM);
#pragma unroll
    for (int i = 0; i < 8; ++i) {
        F4 o;
#pragma unroll
        for (int e = 0; e < 4; ++e) o.a[e] = (acc[i][e] + bv.a[e]) * SCALE;
        *reinterpret_cast<float4*>(&qb[(n0 + i) * CDIM + c0]) = o.v;
    }
}

// One block per output batch b; loops r1 over b2 = 4b + r1.
// Phases per r1: stage x2/q^T -> kv GEMM -> k^T/v to LDS -> per-wave head
// attention (QK^T + bias, softmax, attn store, PV accum in regs).
// After loop: r1-sum in LDS + output projection.
__global__ __launch_bounds__(256, 1) void fused_k(
    const float* __restrict__ x2,  const float* __restrict__ w2,
    const float* __restrict__ b2v, const float* __restrict__ pw,
    const float* __restrict__ pb,  const float* __restrict__ q_ws,
    const float* __restrict__ bias_ws,
    float* __restrict__ out_x, float* __restrict__ out_attn)
{
    // 153,600 B of LDS, phase-aliased:
    //  [0,8192)      xs  [64][128]   f32   (kv phase; aliased by Ps)
    //  [8192,16640)  wch [32][264]/[32][132] (weight chunks; aliased by Ps)
    //  [0,16640)     Ps  [4][64*65]  f32   (attention phase, per-head P)
    //  [16640,25344) qT  [128][68]   f32
    //  [25344,34048) kT  [128][68]   f32   (aliased by ys [64][132] in proj)
    //  [34048,38400) vs  [64][136]   bf16
    __shared__ __align__(16) float smem[38400];
    float*    xs  = smem;
    float*    wch = smem + 8192;
    float*    Ps  = smem;
    float*    qT  = smem + 16640;
    float*    kT  = smem + 25344;
    float*    ys  = smem + 25344;
    uint16_t* vs  = reinterpret_cast<uint16_t*>(smem + 34048);

    const int tid = threadIdx.x;
    const int b   = blockIdx.x;          // output batch 0..2047
    const int tn  = tid >> 5, tc = tid & 31;
    const int wh  = tid >> 6;            // wave id == head
    const int ln  = tid & 63;
    const int gn  = ln >> 3, gq = ln & 7;

    float acc_out[8][4];
#pragma unroll
    for (int i = 0; i < 8; ++i)
#pragma unroll
        for (int e = 0; e < 4; ++e) acc_out[i][e] = 0.f;

    for (int r1 = 0; r1 < RATIO; ++r1) {
        const int b2  = b * RATIO + r1;
        const int b1q = b2 & (NB1 - 1);   // q batch index = (4b+r1) mod 2048

        // ---- phase 0: stage x2 tile + transposed q tile ----
        const float* xb = x2   + (size_t)b2  * (NT * CDIM);
        const float* qb = q_ws + (size_t)b1q * (NT * CDIM);
#pragma unroll
        for (int i = 0; i < 8; ++i) {
            int idx = tid + i * 256;                  // 0..2047
            reinterpret_cast<float4*>(xs)[idx] = reinterpret_cast<const float4*>(xb)[idx];
            int n = idx >> 5, c4 = (idx & 31) * 4;
            F4 q4; q4.v = reinterpret_cast<const float4*>(qb)[idx];
#pragma unroll
            for (int e = 0; e < 4; ++e) qT[(c4 + e) * 68 + n] = q4.a[e];
        }

        // ---- phase 1: kvproj = x2[b2] @ qkv2_w^T + b ----
        float acc[8][8];
#pragma unroll
        for (int i = 0; i < 8; ++i)
#pragma unroll
            for (int e = 0; e < 8; ++e) acc[i][e] = 0.f;
        const int c0 = tc * 8;

        for (int kc = 0; kc < 4; ++kc) {
            __syncthreads();
#pragma unroll
            for (int i = 0; i < 8; ++i) {
                int idx = tid + i * 256;              // 0..2047
                int c = idx >> 3, k4 = idx & 7;
                F4 w4; w4.v = reinterpret_cast<const float4*>(w2 + c * CDIM + kc * 32)[k4];
#pragma unroll
                for (int e = 0; e < 4; ++e) wch[(k4 * 4 + e) * 264 + c] = w4.a[e];
            }
            __syncthreads();
            for (int k4 = 0; k4 < 8; ++k4) {
                const int k = kc * 32 + k4 * 4;
                F4 xv[8];
#pragma unroll
                for (int i = 0; i < 8; ++i)
                    xv[i].v = *reinterpret_cast<const float4*>(&xs[(tn * 8 + i) * CDIM + k]);
#pragma unroll
                for (int kk = 0; kk < 4; ++kk) {
                    F4 wa, wb;
                    wa.v = *reinterpret_cast<const float4*>(&wch[(k4 * 4 + kk) * 264 + c0]);
                    wb.v = *reinterpret_cast<const float4*>(&wch[(k4 * 4 + kk) * 264 + c0 + 4]);
#pragma unroll
                    for (int i = 0; i < 8; ++i) {
                        float xk = xv[i].a[kk];
#pragma unroll
                        for (int e = 0; e < 4; ++e) {
                            acc[i][e]     = fmaf(xk, wa.a[e], acc[i][e]);
                            acc[i][e + 4] = fmaf(xk, wb.a[e], acc[i][e + 4]);
                        }
                    }
                }
            }
        }

        // epilogue: + bias; write k^T (fp32) / v (bf16) into LDS
        {
            F4 ba, bb;
            ba.v = *reinterpret_cast<const float4*>(b2v + c0);
            bb.v = *reinterpret_cast<const float4*>(b2v + c0 + 4);
            float bias8[8];
#pragma unroll
            for (int e = 0; e < 4; ++e) { bias8[e] = ba.a[e]; bias8[e + 4] = bb.a[e]; }
            if (c0 < CDIM) {
#pragma unroll
                for (int cc = 0; cc < 8; ++cc) {
                    const int c = c0 + cc;
                    F4 lo, hi;
#pragma unroll
                    for (int e = 0; e < 4; ++e) {
                        lo.a[e] = acc[e][cc]     + bias8[cc];
                        hi.a[e] = acc[e + 4][cc] + bias8[cc];
                    }
                    *reinterpret_cast<float4*>(&kT[c * 68 + tn * 8])     = lo.v;
                    *reinterpret_cast<float4*>(&kT[c * 68 + tn * 8 + 4]) = hi.v;
                }
            } else {
#pragma unroll
                for (int i = 0; i < 8; ++i) {
                    const int n = tn * 8 + i;
                    uint4 pk;
                    uint32_t* pp = &pk.x;
#pragma unroll
                    for (int e = 0; e < 4; ++e) {
                        uint32_t loq = f2bf(acc[i][2 * e]     + bias8[2 * e]);
                        uint32_t hiq = f2bf(acc[i][2 * e + 1] + bias8[2 * e + 1]);
                        pp[e] = loq | (hiq << 16);
                    }
                    *reinterpret_cast<uint4*>(&vs[n * 136 + (c0 - CDIM)]) = pk;
                }
            }
        }
        __syncthreads();

        // ---- phase 2: attention, one wave per head ----
        {
            const int h  = wh;
            const int n0 = gn * 8, m0 = gq * 8;
            const float* qTh = qT + (h * DHEAD) * 68;
            const float* kTh = kT + (h * DHEAD) * 68;
            float accL[8][8];
#pragma unroll
            for (int i = 0; i < 8; ++i)
#pragma unroll
                for (int m = 0; m < 8; ++m) accL[i][m] = 0.f;

#pragma unroll 4
            for (int j = 0; j < DHEAD; ++j) {
                F4 qa, qb4, ka, kb;
                qa.v  = *reinterpret_cast<const float4*>(&qTh[j * 68 + n0]);
                qb4.v = *reinterpret_cast<const float4*>(&qTh[j * 68 + n0 + 4]);
                ka.v  = *reinterpret_cast<const float4*>(&kTh[j * 68 + m0]);
                kb.v  = *reinterpret_cast<const float4*>(&kTh[j * 68 + m0 + 4]);
                float qv8[8], kv8[8];
#pragma unroll
                for (int e = 0; e < 4; ++e) {
                    qv8[e] = qa.a[e]; qv8[e + 4] = qb4.a[e];
                    kv8[e] = ka.a[e]; kv8[e + 4] = kb.a[e];
                }
#pragma unroll
                for (int i = 0; i < 8; ++i)
#pragma unroll
                    for (int m = 0; m < 8; ++m)
                        accL[i][m] = fmaf(qv8[i], kv8[m], accL[i][m]);
            }

            const float* bh = bias_ws + h * (NT * NT);
            float*       Ph = Ps + h * (NT * 65);
            float*       ab = out_attn + ((size_t)b2 * NHEAD + h) * (NT * NT);
#pragma unroll
            for (int i = 0; i < 8; ++i) {
                const int n = n0 + i;
                F4 ba, bb;
                ba.v = *reinterpret_cast<const float4*>(&bh[n * NT + m0]);
                bb.v = *reinterpret_cast<const float4*>(&bh[n * NT + m0 + 4]);
#pragma unroll
                for (int e = 0; e < 4; ++e) { accL[i][e] += ba.a[e]; accL[i][e + 4] += bb.a[e]; }
                float mx = accL[i][0];
#pragma unroll
                for (int m = 1; m < 8; ++m) mx = fmaxf(mx, accL[i][m]);
                mx = fmaxf(mx, __shfl_xor(mx, 1));
                mx = fmaxf(mx, __shfl_xor(mx, 2));
                mx = fmaxf(mx, __shfl_xor(mx, 4));
                float s = 0.f;
#pragma unroll
                for (int m = 0; m < 8; ++m) { accL[i][m] = __expf(accL[i][m] - mx); s += accL[i][m]; }
                s += __shfl_xor(s, 1);
                s += __shfl_xor(s, 2);
                s += __shfl_xor(s, 4);
                const float inv = 1.0f / s;
                F4 pa, pb4;
#pragma unroll
                for (int m = 0; m < 4; ++m) { pa.a[m] = accL[i][m] * inv; pb4.a[m] = accL[i][m + 4] * inv; }
                *reinterpret_cast<float4*>(&ab[n * NT + m0])     = pa.v;
                *reinterpret_cast<float4*>(&ab[n * NT + m0 + 4]) = pb4.v;
#pragma unroll
                for (int m = 0; m < 4; ++m) {
                    Ph[n * 65 + m0 + m]     = pa.a[m];
                    Ph[n * 65 + m0 + 4 + m] = pb4.a[m];
                }
            }

            // PV: acc_out[rows n0..n0+7][cols 4gq..4gq+3] += P @ v
            const uint16_t* vh = vs + h * DHEAD + gq * 4;
#pragma unroll 8
            for (int m = 0; m < NT; ++m) {
                uint2 vr = *reinterpret_cast<const uint2*>(&vh[m * 136]);
                float v0 = bf2f(vr.x & 0xFFFFu), v1 = bf2f(vr.x >> 16);
                float v2 = bf2f(vr.y & 0xFFFFu), v3 = bf2f(vr.y >> 16);
#pragma unroll
                for (int i = 0; i < 8; ++i) {
                    float p = Ph[(n0 + i) * 65 + m];
                    acc_out[i][0] = fmaf(p, v0, acc_out[i][0]);
                    acc_out[i][1] = fmaf(p, v1, acc_out[i][1]);
                    acc_out[i][2] = fmaf(p, v2, acc_out[i][2]);
                    acc_out[i][3] = fmaf(p, v3, acc_out[i][3]);
                }
            }
        }
        __syncthreads();
    }

    // ---- phase 3: r1-summed rows -> LDS, then x = y @ proj_w^T + proj_b ----
    {
        const int c0o = wh * DHEAD + gq * 4;
        const int n0  = gn * 8;
#pragma unroll
        for (int i = 0; i < 8; ++i) {
            F4 o;
#pragma unroll
            for (int e = 0; e < 4; ++e) o.a[e] = acc_out[i][e];
            *reinterpret_cast<float4*>(&ys[(n0 + i) * 132 + c0o]) = o.v;
        }
    }
    float accp[8][4];
#pragma unroll
    for (int i = 0; i < 8; ++i)
#pragma unroll
        for (int e = 0; e < 4; ++e) accp[i][e] = 0.f;
    const int c0p = tc * 4;
    for (int kc = 0; kc < 4; ++kc) {
        __syncthreads();
#pragma unroll
        for (int i = 0; i < 4; ++i) {
            int idx = tid + i * 256;                  // 0..1023
            int c = idx >> 3, k4 = idx & 7;
            F4 w4; w4.v = reinterpret_cast<const float4*>(pw + c * CDIM + kc * 32)[k4];
#pragma unroll
            for (int e = 0; e < 4; ++e) wch[(k4 * 4 + e) * 132 + c] = w4.a[e];
        }
        __syncthreads();
        for (int k4 = 0; k4 < 8; ++k4) {
            const int k = kc * 32 + k4 * 4;
            F4 yv[8];
#pragma unroll
            for (int i = 0; i < 8; ++i)
                yv[i].v = *reinterpret_cast<const float4*>(&ys[(tn * 8 + i) * 132 + k]);
#pragma unroll
            for (int kk = 0; kk < 4; ++kk) {
                F4 wv4; wv4.v = *reinterpret_cast<const float4*>(&wch[(k4 * 4 + kk) * 132 + c0p]);
#pragma unroll
                for (int i = 0; i < 8; ++i) {
                    float yk = yv[i].a[kk];
#pragma unroll
                    for (int e = 0; e < 4; ++e)
                        accp[i][e] = fmaf(yk, wv4.a[e], accp[i][e]);
                }
            }
        }
    }
    F4 pbv; pbv.v = *reinterpret_cast<const float4*>(pb + c0p);
    float* ob = out_x + (size_t)b * (NT * CDIM);
#pragma unroll
    for (int i = 0; i < 8; ++i) {
        F4 o;
#pragma unroll
        for (int e = 0; e < 4; ++e) o.a[e] = accp[i][e] + pbv.a[e];
        *reinterpret_cast<float4*>(&ob[(tn * 8 + i) * CDIM + c0p]) = o.v;
    }
}

extern "C" void kernel_launch(void* const* d_in, const int* in_sizes, int n_in,
                              void* d_out, int out_size, void* d_ws, size_t ws_size,
                              hipStream_t stream) {
    (void)in_sizes; (void)n_in; (void)out_size; (void)ws_size;
    const float* x1  = (const float*)d_in[0];
    const float* x2  = (const float*)d_in[1];
    const float* w1  = (const float*)d_in[2];
    const float* b1v = (const float*)d_in[3];
    const float* w2  = (const float*)d_in[4];
    const float* b2v = (const float*)d_in[5];
    const float* pw  = (const float*)d_in[6];
    const float* pb  = (const float*)d_in[7];
    const float* rpb = (const float*)d_in[8];
    const int*   rel = (const int*)d_in[9];
    // d_in[10] = num_heads (compile-time constant 4 here)

    float* out_x    = (float*)d_out;
    float* out_attn = out_x + (size_t)NB1 * NT * CDIM;   // x first, then attn

    float* q_ws    = (float*)d_ws;                        // 2048*64*128 floats
    float* bias_ws = q_ws + (size_t)NB1 * NT * CDIM;      // 4*64*64 floats

    bias_prep_k<<<64,  256, 0, stream>>>(rpb, rel, bias_ws);
    q_proj_k  <<<NB1, 256, 0, stream>>>(x1, w1, b1v, q_ws);
    fused_k   <<<NB1, 256, 0, stream>>>(x2, w2, b2v, pw, pb, q_ws, bias_ws,
                                        out_x, out_attn);
}